// Round 1
// baseline (178.168 us; speedup 1.0000x reference)
//
#include <hip/hip_runtime.h>

constexpr int BATCH = 131072;
constexpr int T = 10;
constexpr int H = 32;

__device__ __forceinline__ float fast_tanh(float v) {
    // tanh(v) = 1 - 2/(exp(2v)+1); exp overflow -> inf -> rcp -> 0 -> +1 (correct)
    float e = __expf(2.0f * v);
    return 1.0f - 2.0f * __builtin_amdgcn_rcpf(e + 1.0f);
}

extern "C" __global__ void __launch_bounds__(256)
rnn_fused(const float* __restrict__ x,      // [B, T, 1]
          const float* __restrict__ h0,     // [1, B, H]
          const float* __restrict__ W_ih,   // [H, 1]
          const float* __restrict__ W_hh,   // [H, H] row-major: W_hh[j*H+k]
          const float* __restrict__ b_ih,   // [H]
          const float* __restrict__ b_hh,   // [H]
          const float* __restrict__ W_out,  // [1, H]
          const float* __restrict__ b_out,  // [1]
          float* __restrict__ out)          // outs [B*T] then hT [B*H]
{
    __shared__ float sWt[H * H];   // transposed: sWt[k*H + j] = W_hh[j*H + k]
    __shared__ float sWih[H];
    __shared__ float sWout[H];
    __shared__ float sBias[H];
    __shared__ float sBout;

    const int tid = threadIdx.x;
    for (int i = tid; i < H * H; i += 256) {
        const int j = i >> 5, k = i & 31;
        sWt[k * H + j] = W_hh[i];
    }
    if (tid < H) {
        sWih[tid]  = W_ih[tid];
        sWout[tid] = W_out[tid];
        sBias[tid] = b_ih[tid] + b_hh[tid];
    }
    if (tid == 0) sBout = b_out[0];
    __syncthreads();

    const int b = blockIdx.x * 256 + tid;

    // load initial hidden state (contiguous 128B per lane, float4 x8)
    float h[H];
    {
        const float4* hp = reinterpret_cast<const float4*>(h0 + (size_t)b * H);
        #pragma unroll
        for (int i = 0; i < H / 4; ++i) {
            float4 v = hp[i];
            h[4*i+0] = v.x; h[4*i+1] = v.y; h[4*i+2] = v.z; h[4*i+3] = v.w;
        }
    }

    const float* xb = x + (size_t)b * T;
    float*       ob = out + (size_t)b * T;

    float xt = xb[0];

    #pragma unroll 1
    for (int t = 0; t < T; ++t) {
        // software-pipelined next-x load (hidden under the ~1.3k-instr body)
        float xnext = (t + 1 < T) ? xb[t + 1] : 0.0f;

        float acc[H];
        #pragma unroll
        for (int j = 0; j < H; ++j) acc[j] = fmaf(xt, sWih[j], sBias[j]);

        // acc[j] += sum_k h[k] * W_hh[j][k], via transposed LDS rows (uniform
        // broadcast reads, conflict-free)
        #pragma unroll
        for (int k = 0; k < H; ++k) {
            const float hk = h[k];
            const float4* wr = reinterpret_cast<const float4*>(&sWt[k * H]);
            #pragma unroll
            for (int q = 0; q < H / 4; ++q) {
                float4 w = wr[q];
                acc[4*q+0] = fmaf(hk, w.x, acc[4*q+0]);
                acc[4*q+1] = fmaf(hk, w.y, acc[4*q+1]);
                acc[4*q+2] = fmaf(hk, w.z, acc[4*q+2]);
                acc[4*q+3] = fmaf(hk, w.w, acc[4*q+3]);
            }
        }

        float o = sBout;
        #pragma unroll
        for (int j = 0; j < H; ++j) {
            float hn = fast_tanh(acc[j]);
            h[j] = hn;
            o = fmaf(hn, sWout[j], o);
        }
        ob[t] = o;
        xt = xnext;
    }

    // write final hidden state
    float4* hout = reinterpret_cast<float4*>(out + (size_t)BATCH * T + (size_t)b * H);
    #pragma unroll
    for (int i = 0; i < H / 4; ++i) {
        float4 v;
        v.x = h[4*i+0]; v.y = h[4*i+1]; v.z = h[4*i+2]; v.w = h[4*i+3];
        hout[i] = v;
    }
}

extern "C" void kernel_launch(void* const* d_in, const int* in_sizes, int n_in,
                              void* d_out, int out_size, void* d_ws, size_t ws_size,
                              hipStream_t stream) {
    const float* x     = (const float*)d_in[0];
    const float* h0    = (const float*)d_in[1];
    const float* W_ih  = (const float*)d_in[2];
    const float* W_hh  = (const float*)d_in[3];
    const float* b_ih  = (const float*)d_in[4];
    const float* b_hh  = (const float*)d_in[5];
    const float* W_out = (const float*)d_in[6];
    const float* b_out = (const float*)d_in[7];
    float* out = (float*)d_out;

    rnn_fused<<<BATCH / 256, 256, 0, stream>>>(
        x, h0, W_ih, W_hh, b_ih, b_hh, W_out, b_out, out);
}

// Round 2
// 108.216 us; speedup vs baseline: 1.6464x; 1.6464x over previous
//
#include <hip/hip_runtime.h>

constexpr int BATCH = 131072;
constexpr int T = 10;
constexpr int H = 32;

__device__ __forceinline__ float fast_tanh(float v) {
    // tanh(v) = 1 - 2/(exp(2v)+1); exp overflow -> inf -> rcp -> 0 -> +1 (correct)
    float e = __expf(2.0f * v);
    return 1.0f - 2.0f * __builtin_amdgcn_rcpf(e + 1.0f);
}

extern "C" __global__ void __launch_bounds__(256)
rnn_fused(const float* __restrict__ x,      // [B, T, 1]
          const float* __restrict__ h0,     // [1, B, H]
          const float* __restrict__ W_ih,   // [H, 1]
          const float* __restrict__ W_hh,   // [H, H] row-major: W_hh[j*H+k]
          const float* __restrict__ b_ih,   // [H]
          const float* __restrict__ b_hh,   // [H]
          const float* __restrict__ W_out,  // [1, H]
          const float* __restrict__ b_out,  // [1]
          float* __restrict__ out)          // outs [B*T] then hT [B*H]
{
    const int b = blockIdx.x * 256 + threadIdx.x;

    // initial hidden state: contiguous float4 x8 per lane (coalesced 128B)
    float h[H];
    {
        const float4* hp = reinterpret_cast<const float4*>(h0 + (size_t)b * H);
        #pragma unroll
        for (int i = 0; i < H / 4; ++i) {
            float4 v = hp[i];
            h[4*i+0] = v.x; h[4*i+1] = v.y; h[4*i+2] = v.z; h[4*i+3] = v.w;
        }
    }

    const float* xb = x + (size_t)b * T;
    float*       ob = out + (size_t)b * T;

    float xt = xb[0];

    #pragma unroll 1
    for (int t = 0; t < T; ++t) {
        float xnext = (t + 1 < T) ? xb[t + 1] : 0.0f;

        // All weight/bias reads below have wave-uniform addresses with
        // compile-time indices -> scalar loads (s_load) through the constant
        // cache; v_fma_f32 takes the SGPR as src. No LDS, no per-lane VMEM.
        float hn[H];
        #pragma unroll
        for (int j = 0; j < H; ++j) {
            float a = fmaf(xt, W_ih[j], b_ih[j] + b_hh[j]);
            const float* wr = W_hh + j * H;   // contiguous 128B row -> s_load_dwordx16 pairs
            #pragma unroll
            for (int k = 0; k < H; ++k)
                a = fmaf(h[k], wr[k], a);
            hn[j] = fast_tanh(a);
        }

        float o = b_out[0];
        #pragma unroll
        for (int j = 0; j < H; ++j) {
            o = fmaf(hn[j], W_out[j], o);
            h[j] = hn[j];
        }
        ob[t] = o;
        xt = xnext;
    }

    // final hidden state
    float4* hout = reinterpret_cast<float4*>(out + (size_t)BATCH * T + (size_t)b * H);
    #pragma unroll
    for (int i = 0; i < H / 4; ++i) {
        float4 v;
        v.x = h[4*i+0]; v.y = h[4*i+1]; v.z = h[4*i+2]; v.w = h[4*i+3];
        hout[i] = v;
    }
}

extern "C" void kernel_launch(void* const* d_in, const int* in_sizes, int n_in,
                              void* d_out, int out_size, void* d_ws, size_t ws_size,
                              hipStream_t stream) {
    const float* x     = (const float*)d_in[0];
    const float* h0    = (const float*)d_in[1];
    const float* W_ih  = (const float*)d_in[2];
    const float* W_hh  = (const float*)d_in[3];
    const float* b_ih  = (const float*)d_in[4];
    const float* b_hh  = (const float*)d_in[5];
    const float* W_out = (const float*)d_in[6];
    const float* b_out = (const float*)d_in[7];
    float* out = (float*)d_out;

    rnn_fused<<<BATCH / 256, 256, 0, stream>>>(
        x, h0, W_ih, W_hh, b_ih, b_hh, W_out, b_out, out);
}